// Round 6
// baseline (830.326 us; speedup 1.0000x reference)
//
#include <hip/hip_runtime.h>
#include <math.h>

#define RMINF  0.5f
#define LSPAN  5.5f          // RC - RMIN
constexpr int BETA = 12, M1 = 24, M2 = 6;
constexpr int B_ = 4, N_ = 1024, NT_ = 2, MN_ = 128;
constexpr int K_ = NT_ * MN_;        // 256
constexpr int NFEAT = M1 * M2;       // 144
constexpr int HID = 128;
constexpr float PI_F = 3.14159265358979323846f;

// Output layout: Etot(4) | Ei(4096) | Force(4*1024*3) | Virial(36)
constexpr int EI_OFF = B_;                  // 4
constexpr int F_OFF  = B_ + B_ * N_;        // 4100
constexpr int V_OFF  = F_OFF + B_ * N_ * 3; // 16388

constexpr int G_ = 4;                 // source atoms per k3 block
constexpr int NG = B_ * N_ / G_;      // 1024 k3 blocks
constexpr int SL = 8;                 // reduce slices

// Workspace layout (floats); total ~16.9 MB
constexpr size_t WS_FEAT    = 0;                          // 4096*144
constexpr size_t WS_R       = (size_t)B_ * N_ * NFEAT;    // 4096*96
constexpr size_t WS_VIR     = WS_R + (size_t)B_ * N_ * 96;      // 1024*9
constexpr size_t WS_CONTRIB = WS_VIR + (size_t)NG * 9;          // 1024*3072
constexpr size_t WS_PARTIAL = WS_CONTRIB + (size_t)NG * N_ * 3; // 8*4*3072

// ---------------- K1: embedding forward -> feat, R ----------------
__global__ __launch_bounds__(256, 4) void k1_embed(
    const int*   __restrict__ list_neigh,
    const int*   __restrict__ type_map,
    const float* __restrict__ imagedr,
    const float* __restrict__ c_param,
    const float* __restrict__ scale,
    float* __restrict__ feat_ws,
    float* __restrict__ R_ws)
{
    __shared__ float c_sh[NT_ * M1 * BETA];
    __shared__ float s_sh[K_ * 25];
    __shared__ float sr_sh[K_ * 5];
    __shared__ float Rpart[2 * 96];
    __shared__ float R_sh[96];

    const int tid = threadIdx.x;
    const int bn = blockIdx.x;
    const int n  = bn % N_;
    const int tn = type_map[n];

    for (int i = tid; i < NT_ * M1 * BETA; i += 256)
        c_sh[i] = c_param[tn * (NT_ * M1 * BETA) + i];

    const int k  = tid;
    const int tk = k >> 7;
    const int lni = list_neigh[(size_t)bn * K_ + k];
    const float valid = (lni >= 0) ? 1.0f : 0.0f;

    const float4 dr4 = reinterpret_cast<const float4*>(imagedr)[(size_t)bn * K_ + k];
    const float rx = dr4.y, ry = dr4.z, rz = dr4.w;
    const float r  = sqrtf(rx*rx + ry*ry + rz*rz + 1e-12f);
    const float uraw = (r - RMINF) / LSPAN;
    const float u  = fminf(fmaxf(uraw, 0.0f), 1.0f);
    const float fc = 0.5f * (cosf(PI_F * u) + 1.0f) * valid;
    const float x  = 2.0f * (r - RMINF) / LSPAN - 1.0f;

    float T[BETA];
    T[0] = 1.0f; T[1] = x;
#pragma unroll
    for (int j = 2; j < BETA; ++j) T[j] = 2.0f * x * T[j-1] - T[j-2];

    const float inv_r = 1.0f / r;
    sr_sh[k * 5 + 0] = valid;
    sr_sh[k * 5 + 1] = valid * rx * inv_r;
    sr_sh[k * 5 + 2] = valid * ry * inv_r;
    sr_sh[k * 5 + 3] = valid * rz * inv_r;

    __syncthreads();   // c_sh ready

    const float* crow = &c_sh[tk * M1 * BETA];
#pragma unroll
    for (int f = 0; f < M1; ++f) {
        float a0 = 0.0f, a1 = 0.0f;
#pragma unroll
        for (int j = 0; j < BETA; j += 2) {
            a0 = fmaf(T[j],   crow[f * BETA + j],   a0);
            a1 = fmaf(T[j+1], crow[f * BETA + j+1], a1);
        }
        s_sh[k * 25 + f] = fc * (a0 + a1);
    }
    __syncthreads();

    if (tid < 192) {
        const int half = tid / 96, tt = tid % 96;
        const int f = tt >> 2, c = tt & 3;
        const int k0 = half * 128;
        float a0 = 0.0f, a1 = 0.0f;
        for (int kk = k0; kk < k0 + 128; kk += 2) {
            a0 = fmaf(s_sh[kk * 25 + f],     sr_sh[kk * 5 + c],     a0);
            a1 = fmaf(s_sh[(kk+1) * 25 + f], sr_sh[(kk+1) * 5 + c], a1);
        }
        Rpart[half * 96 + tt] = a0 + a1;
    }
    __syncthreads();
    if (tid < 96) {
        const float v = (Rpart[tid] + Rpart[96 + tid]) * (1.0f / MN_);
        R_sh[tid] = v;
        R_ws[(size_t)bn * 96 + tid] = v;
    }
    __syncthreads();
    if (tid < NFEAT) {
        const int f = tid / 6, g = tid % 6;
        float acc = 0.0f;
#pragma unroll
        for (int c = 0; c < 4; ++c) acc += R_sh[f * 4 + c] * R_sh[g * 4 + c];
        feat_ws[(size_t)bn * NFEAT + tid] = acc * scale[tid];
    }
}

// ---------------- K2: MLP fwd + bwd (2 atoms per block) ----------------
__global__ __launch_bounds__(256, 4) void k2_mlp(
    const int*   __restrict__ type_map,
    const float* __restrict__ scale,
    const float* __restrict__ W0,
    const float* __restrict__ b0,
    const float* __restrict__ W1,
    const float* __restrict__ b1,
    const float* __restrict__ W2,
    const float* __restrict__ b2,
    const float* __restrict__ eshift,
    const float* __restrict__ feat_ws,
    float* __restrict__ dfeat_ws,     // may alias feat_ws
    float* __restrict__ out)
{
    __shared__ float feat_sh[2][NFEAT];
    __shared__ float h_sh[2][HID];
    __shared__ float dz1_sh[2][HID];
    __shared__ float dz0_sh[2][HID];
    __shared__ float red[4];

    const int tid = threadIdx.x;
    const int a   = tid >> 7;          // atom slot 0/1
    const int c   = tid & 127;         // column / row index
    const int lane = tid & 63;
    const int wid  = tid >> 6;
    const int bn = blockIdx.x * 2 + a;
    const int n  = bn % N_;
    const int tn = type_map[n];

    for (int i = tid; i < 2 * NFEAT; i += 256) {
        const int aa = i / NFEAT, f = i % NFEAT;
        feat_sh[aa][f] = feat_ws[(size_t)(blockIdx.x * 2 + aa) * NFEAT + f];
    }
    __syncthreads();

    // layer 0
    float acc0 = b0[tn * HID + c], acc0b = 0.0f;
    const float* w0c = W0 + (size_t)tn * NFEAT * HID + c;
#pragma unroll 8
    for (int f = 0; f < NFEAT; f += 2) {
        acc0  = fmaf(feat_sh[a][f],   w0c[f * HID],       acc0);
        acc0b = fmaf(feat_sh[a][f+1], w0c[(f+1) * HID],   acc0b);
    }
    const float h = tanhf(acc0 + acc0b);
    h_sh[a][c] = h;
    __syncthreads();

    // layer 1
    float acc1 = b1[tn * HID + c], acc1b = 0.0f;
    const float* w1c = W1 + (size_t)tn * HID * HID + c;
#pragma unroll 8
    for (int g = 0; g < HID; g += 2) {
        acc1  = fmaf(h_sh[a][g],   w1c[g * HID],       acc1);
        acc1b = fmaf(h_sh[a][g+1], w1c[(g+1) * HID],   acc1b);
    }
    const float t1 = tanhf(acc1 + acc1b);
    const float w2c = W2[tn * HID + c];
    const float dz1 = w2c * (1.0f - t1 * t1);
    dz1_sh[a][c] = dz1;

    // Ei = sum over c of (t1+h)*w2c
    {
        float v = (t1 + h) * w2c;
#pragma unroll
        for (int m = 32; m >= 1; m >>= 1) v += __shfl_xor(v, m);
        if (lane == 0) red[wid] = v;
    }
    __syncthreads();
    if (c == 0)
        out[EI_OFF + bn] = red[a * 2] + red[a * 2 + 1] + b2[tn] + eshift[tn];

    // dz0[h] = (W2[h] + sum_g W1[h][g]*dz1[g]) * (1-h^2)
    {
        const float4* w1row = reinterpret_cast<const float4*>(W1 + (size_t)(tn * HID + c) * HID);
        float ar = w2c, arb = 0.0f;
#pragma unroll 4
        for (int g4 = 0; g4 < HID / 4; g4 += 2) {
            const float4 w  = w1row[g4];
            const float4 w2 = w1row[g4 + 1];
            ar  += w.x  * dz1_sh[a][g4*4+0] + w.y  * dz1_sh[a][g4*4+1]
                 + w.z  * dz1_sh[a][g4*4+2] + w.w  * dz1_sh[a][g4*4+3];
            arb += w2.x * dz1_sh[a][g4*4+4] + w2.y * dz1_sh[a][g4*4+5]
                 + w2.z * dz1_sh[a][g4*4+6] + w2.w * dz1_sh[a][g4*4+7];
        }
        dz0_sh[a][c] = (ar + arb) * (1.0f - h * h);
    }
    __syncthreads();

    // dfeat[f] = scale[f] * sum_h W0[f][h] * dz0[h]
    for (int f = c; f < NFEAT; f += 128) {
        const float4* w0row = reinterpret_cast<const float4*>(W0 + (size_t)(tn * NFEAT + f) * HID);
        float ar = 0.0f, arb = 0.0f;
#pragma unroll 4
        for (int h4 = 0; h4 < HID / 4; h4 += 2) {
            const float4 w  = w0row[h4];
            const float4 w2 = w0row[h4 + 1];
            ar  += w.x  * dz0_sh[a][h4*4+0] + w.y  * dz0_sh[a][h4*4+1]
                 + w.z  * dz0_sh[a][h4*4+2] + w.w  * dz0_sh[a][h4*4+3];
            arb += w2.x * dz0_sh[a][h4*4+4] + w2.y * dz0_sh[a][h4*4+5]
                 + w2.z * dz0_sh[a][h4*4+6] + w2.w * dz0_sh[a][h4*4+7];
        }
        dfeat_ws[(size_t)bn * NFEAT + f] = (ar + arb) * scale[f];
    }
}

// ---------------- K3: embedding backward, G_ atoms/block, LDS force image ----------------
__global__ __launch_bounds__(256, 4) void k3_bwd(
    const int*   __restrict__ list_neigh,
    const int*   __restrict__ type_map,
    const float* __restrict__ imagedr,
    const float* __restrict__ c_param,
    const float* __restrict__ dfeat_ws,
    const float* __restrict__ R_ws,
    float* __restrict__ contrib_ws,
    float* __restrict__ vir_ws)
{
    __shared__ float fcontrib[N_ * 3];      // 12 KB: force image for this batch
    __shared__ float c_sh[NT_ * M1 * BETA]; // 2.3 KB
    __shared__ float dfeat_sh[NFEAT];
    __shared__ float R_sh[96];
    __shared__ float dR_sh[96];
    __shared__ float red12[12 * 4];

    const int tid  = threadIdx.x;
    const int lane = tid & 63;
    const int wid  = tid >> 6;
    const int g  = blockIdx.x;            // 0..NG-1
    const int tk = tid >> 7;

    for (int i = tid; i < N_ * 3; i += 256) fcontrib[i] = 0.0f;

    float vv0=0.f,vv1=0.f,vv2=0.f,vv3=0.f,vv4=0.f,vv5=0.f,vv6=0.f,vv7=0.f,vv8=0.f;

    for (int aa = 0; aa < G_; ++aa) {
        const int bn = g * G_ + aa;
        const int n  = bn & (N_ - 1);
        const int tn = type_map[n];

        __syncthreads();   // previous iteration's users of shared bufs done
        for (int i = tid; i < NT_ * M1 * BETA; i += 256)
            c_sh[i] = c_param[tn * (NT_ * M1 * BETA) + i];
        if (tid < NFEAT) dfeat_sh[tid] = dfeat_ws[(size_t)bn * NFEAT + tid];
        if (tid < 96)    R_sh[tid]     = R_ws[(size_t)bn * 96 + tid];
        __syncthreads();

        if (tid < 96) {
            const int p = tid >> 2, c = tid & 3;
            float acc = 0.0f;
#pragma unroll
            for (int gg = 0; gg < M2; ++gg) acc += dfeat_sh[p * 6 + gg] * R_sh[gg * 4 + c];
            if (p < M2) {
                for (int f = 0; f < M1; ++f) acc += dfeat_sh[f * 6 + p] * R_sh[f * 4 + c];
            }
            dR_sh[p * 4 + c] = acc * (1.0f / MN_);
        }
        __syncthreads();

        const int lni = list_neigh[(size_t)bn * K_ + tid];
        const float valid = (lni >= 0) ? 1.0f : 0.0f;
        const float4 dr4 = reinterpret_cast<const float4*>(imagedr)[(size_t)bn * K_ + tid];
        const float rx = dr4.y, ry = dr4.z, rz = dr4.w;
        const float r  = sqrtf(rx*rx + ry*ry + rz*rz + 1e-12f);
        const float uraw = (r - RMINF) / LSPAN;
        const float u  = fminf(fmaxf(uraw, 0.0f), 1.0f);
        const float fc = 0.5f * (cosf(PI_F * u) + 1.0f) * valid;
        const float x  = 2.0f * (r - RMINF) / LSPAN - 1.0f;

        float T[BETA];
        T[0] = 1.0f; T[1] = x;
#pragma unroll
        for (int j = 2; j < BETA; ++j) T[j] = 2.0f * x * T[j-1] - T[j-2];

        const float inv_r = 1.0f / r;
        const float sr0 = valid;
        const float sr1 = valid * rx * inv_r;
        const float sr2 = valid * ry * inv_r;
        const float sr3 = valid * rz * inv_r;

        const float* crow = &c_sh[tk * M1 * BETA];
        float cj[BETA];
#pragma unroll
        for (int j = 0; j < BETA; ++j) cj[j] = 0.0f;
        float dsr1 = 0.0f, dsr2 = 0.0f, dsr3 = 0.0f, dfc = 0.0f;
#pragma unroll
        for (int f = 0; f < M1; ++f) {
            float sa = 0.0f, sb = 0.0f;
#pragma unroll
            for (int j = 0; j < BETA; j += 2) {
                sa = fmaf(T[j],   crow[f * BETA + j],   sa);
                sb = fmaf(T[j+1], crow[f * BETA + j+1], sb);
            }
            const float sf = sa + sb;
            const float d0 = dR_sh[f*4+0], d1 = dR_sh[f*4+1], d2 = dR_sh[f*4+2], d3 = dR_sh[f*4+3];
            const float dsf = d0 * sr0 + d1 * sr1 + d2 * sr2 + d3 * sr3;
            dfc += dsf * sf;
            const float dsg = dsf * fc;
#pragma unroll
            for (int j = 0; j < BETA; ++j) cj[j] = fmaf(dsg, crow[f * BETA + j], cj[j]);
            const float sk = fc * sf;
            dsr1 = fmaf(d1, sk, dsr1); dsr2 = fmaf(d2, sk, dsr2); dsr3 = fmaf(d3, sk, dsr3);
        }
        float dx = cj[1];
        float tpm1 = 1.0f, tpm2 = 0.0f;
#pragma unroll
        for (int j = 2; j < BETA; ++j) {
            const float tp = 2.0f * T[j-1] + 2.0f * x * tpm1 - tpm2;
            dx = fmaf(cj[j], tp, dx);
            tpm2 = tpm1; tpm1 = tp;
        }
        float dfcdr = 0.0f;
        if (uraw > 0.0f && uraw < 1.0f)
            dfcdr = -0.5f * PI_F * sinf(PI_F * u) * valid / LSPAN;
        const float drt = dx * (2.0f / LSPAN) + dfc * dfcdr;
        const float Sdot = dsr1 * rx + dsr2 * ry + dsr3 * rz;
        const float common = drt * inv_r - valid * Sdot * inv_r * inv_r * inv_r;
        const float gx = common * rx + valid * dsr1 * inv_r;
        const float gy = common * ry + valid * dsr2 * inv_r;
        const float gz = common * rz + valid * dsr3 * inv_r;

        // neighbor scatter into LDS force image
        if (lni >= 0) {
            atomicAdd(&fcontrib[lni * 3 + 0], -gx);
            atomicAdd(&fcontrib[lni * 3 + 1], -gy);
            atomicAdd(&fcontrib[lni * 3 + 2], -gz);
        }

        // self-force: block reduce then one LDS add
        {
            float s0 = gx, s1 = gy, s2 = gz;
#pragma unroll
            for (int m = 32; m >= 1; m >>= 1) {
                s0 += __shfl_xor(s0, m);
                s1 += __shfl_xor(s1, m);
                s2 += __shfl_xor(s2, m);
            }
            if (lane == 0) {
                red12[0 * 4 + wid] = s0;
                red12[1 * 4 + wid] = s1;
                red12[2 * 4 + wid] = s2;
            }
        }
        __syncthreads();
        if (tid < 3) {
            const float v = red12[tid*4+0] + red12[tid*4+1] + red12[tid*4+2] + red12[tid*4+3];
            atomicAdd(&fcontrib[n * 3 + tid], v);
        }

        // virial accumulate (per-thread, across atoms)
        vv0 = fmaf(-rx, gx, vv0); vv1 = fmaf(-rx, gy, vv1); vv2 = fmaf(-rx, gz, vv2);
        vv3 = fmaf(-ry, gx, vv3); vv4 = fmaf(-ry, gy, vv4); vv5 = fmaf(-ry, gz, vv5);
        vv6 = fmaf(-rz, gx, vv6); vv7 = fmaf(-rz, gy, vv7); vv8 = fmaf(-rz, gz, vv8);
    }

    // virial block reduce -> vir_ws[g][9]
    {
        float vals[9] = {vv0,vv1,vv2,vv3,vv4,vv5,vv6,vv7,vv8};
        __syncthreads();   // red12 free
#pragma unroll
        for (int i = 0; i < 9; ++i) {
            float v = vals[i];
#pragma unroll
            for (int m = 32; m >= 1; m >>= 1) v += __shfl_xor(v, m);
            if (lane == 0) red12[i * 4 + wid] = v;
        }
        __syncthreads();
        if (tid < 9)
            vir_ws[(size_t)g * 9 + tid] = red12[tid*4+0] + red12[tid*4+1]
                                        + red12[tid*4+2] + red12[tid*4+3];
    }

    // flush LDS force image -> contrib (coalesced, non-atomic)
    __syncthreads();
    {
        float4* dst = reinterpret_cast<float4*>(contrib_ws + (size_t)g * (N_ * 3));
        const float4* src = reinterpret_cast<const float4*>(fcontrib);
        for (int i = tid; i < (N_ * 3) / 4; i += 256) dst[i] = src[i];
    }
}

// ---------------- K3R: sliced column-sum of contrib ----------------
__global__ __launch_bounds__(256) void k3_reduce(
    const float* __restrict__ contrib_ws,
    float* __restrict__ partial_ws)
{
    const int x  = blockIdx.x;          // SL*B_*3 blocks
    const int ch = x % 3;
    const int bb = (x / 3) % B_;
    const int s  = x / (3 * B_);
    const int c4 = ch * 256 + threadIdx.x;        // float4 column, 0..767
    const int rows = (NG / B_) / SL;              // 256/8 = 32 rows per slice
    const int g0 = bb * (NG / B_) + s * rows;

    const float4* src = reinterpret_cast<const float4*>(contrib_ws);
    float4 a0 = {0,0,0,0}, a1 = {0,0,0,0};
    for (int r = 0; r < rows; r += 2) {
        const float4 v0 = src[(size_t)(g0 + r)     * 768 + c4];
        const float4 v1 = src[(size_t)(g0 + r + 1) * 768 + c4];
        a0.x += v0.x; a0.y += v0.y; a0.z += v0.z; a0.w += v0.w;
        a1.x += v1.x; a1.y += v1.y; a1.z += v1.z; a1.w += v1.w;
    }
    const float4 res = {a0.x + a1.x, a0.y + a1.y, a0.z + a1.z, a0.w + a1.w};
    reinterpret_cast<float4*>(partial_ws)[(size_t)(s * B_ + bb) * 768 + c4] = res;
}

// ---------------- K4: finalize Force, Etot, Virial ----------------
__global__ __launch_bounds__(256) void k4_final(
    const float* __restrict__ vir_ws,
    const float* __restrict__ partial_ws,
    float* __restrict__ out)
{
    __shared__ float red[10 * 4];
    const int tid  = threadIdx.x;
    const int lane = tid & 63;
    const int wid  = tid >> 6;
    const int b = blockIdx.x;

    // Force: merge SL slice partials, write directly (no zero pass needed)
    for (int i = tid; i < N_ * 3; i += 256) {
        float f = 0.0f;
#pragma unroll
        for (int s = 0; s < SL; ++s) f += partial_ws[(size_t)(s * B_ + b) * (N_ * 3) + i];
        out[F_OFF + (size_t)b * (N_ * 3) + i] = f;
    }

    float vals[10];
#pragma unroll
    for (int i = 0; i < 10; ++i) vals[i] = 0.0f;
    for (int n = tid; n < N_; n += 256) vals[0] += out[EI_OFF + b * N_ + n];
    {   // one vir row per thread (256 rows per batch)
        const float* vp = vir_ws + ((size_t)b * (NG / B_) + tid) * 9;
#pragma unroll
        for (int j = 0; j < 9; ++j) vals[1 + j] = vp[j];
    }
#pragma unroll
    for (int i = 0; i < 10; ++i) {
        float v = vals[i];
#pragma unroll
        for (int m = 32; m >= 1; m >>= 1) v += __shfl_xor(v, m);
        if (lane == 0) red[i * 4 + wid] = v;
    }
    __syncthreads();
    if (tid < 10) {
        const float v = red[tid*4+0] + red[tid*4+1] + red[tid*4+2] + red[tid*4+3];
        if (tid == 0) out[b] = v;
        else          out[V_OFF + b * 9 + (tid - 1)] = v;
    }
}

extern "C" void kernel_launch(void* const* d_in, const int* in_sizes, int n_in,
                              void* d_out, int out_size, void* d_ws, size_t ws_size,
                              hipStream_t stream) {
    float* out = (float*)d_out;
    float* ws  = (float*)d_ws;
    float* feat_ws    = ws + WS_FEAT;
    float* R_ws       = ws + WS_R;
    float* vir_ws     = ws + WS_VIR;
    float* contrib_ws = ws + WS_CONTRIB;
    float* partial_ws = ws + WS_PARTIAL;

    const int*   list_neigh = (const int*)d_in[0];
    const int*   type_map   = (const int*)d_in[1];
    const float* imagedr    = (const float*)d_in[3];
    const float* c_param    = (const float*)d_in[6];
    const float* scale      = (const float*)d_in[7];
    const float* W0 = (const float*)d_in[8];
    const float* b0 = (const float*)d_in[9];
    const float* W1 = (const float*)d_in[10];
    const float* b1 = (const float*)d_in[11];
    const float* W2 = (const float*)d_in[12];
    const float* b2 = (const float*)d_in[13];
    const float* eshift = (const float*)d_in[14];

    k1_embed<<<B_ * N_, 256, 0, stream>>>(list_neigh, type_map, imagedr, c_param,
                                          scale, feat_ws, R_ws);
    k2_mlp<<<B_ * N_ / 2, 256, 0, stream>>>(type_map, scale, W0, b0, W1, b1, W2, b2,
                                            eshift, feat_ws, feat_ws /*alias dfeat*/, out);
    k3_bwd<<<NG, 256, 0, stream>>>(list_neigh, type_map, imagedr, c_param,
                                   feat_ws /*dfeat*/, R_ws, contrib_ws, vir_ws);
    k3_reduce<<<SL * B_ * 3, 256, 0, stream>>>(contrib_ws, partial_ws);
    k4_final<<<B_, 256, 0, stream>>>(vir_ws, partial_ws, out);
}

// Round 8
// 322.816 us; speedup vs baseline: 2.5721x; 2.5721x over previous
//
#include <hip/hip_runtime.h>
#include <math.h>

#define RMINF  0.5f
#define LSPAN  5.5f          // RC - RMIN
constexpr int BETA = 12, M1 = 24, M2 = 6;
constexpr int B_ = 4, N_ = 1024, NT_ = 2, MN_ = 128;
constexpr int K_ = NT_ * MN_;        // 256
constexpr int NFEAT = M1 * M2;       // 144
constexpr int HID = 128;
constexpr float PI_F = 3.14159265358979323846f;

// Output layout: Etot(4) | Ei(4096) | Force(4*1024*3) | Virial(36)
constexpr int EI_OFF = B_;                  // 4
constexpr int F_OFF  = B_ + B_ * N_;        // 4100
constexpr int V_OFF  = F_OFF + B_ * N_ * 3; // 16388

constexpr int G_ = 4;                 // source atoms per k3 block
constexpr int NG = B_ * N_ / G_;      // 1024 k3 blocks
constexpr int SL = 8;                 // reduce slices

// Workspace layout (floats); total ~16.9 MB
constexpr size_t WS_FEAT    = 0;                          // 4096*144
constexpr size_t WS_R       = (size_t)B_ * N_ * NFEAT;    // 4096*96
constexpr size_t WS_VIR     = WS_R + (size_t)B_ * N_ * 96;      // 1024*9
constexpr size_t WS_CONTRIB = WS_VIR + (size_t)NG * 9;          // 1024*3072
constexpr size_t WS_PARTIAL = WS_CONTRIB + (size_t)NG * N_ * 3; // 8*4*3072

// NOTE: no occupancy-floor arg on launch_bounds. (256,4) capped the allocator
// at 64 VGPR -> cj[12]/T[12] spilled to scratch -> ~2 GB HBM traffic in k3
// (rounds 4/6: WRITE_SIZE 1.3 GB at VGPR_Count=64; round-1 fused kernel at
// VGPR=232 moved only 71 MB with identical math).

// ---------------- K1: embedding forward -> feat, R ----------------
__global__ __launch_bounds__(256) void k1_embed(
    const int*   __restrict__ list_neigh,
    const int*   __restrict__ type_map,
    const float* __restrict__ imagedr,
    const float* __restrict__ c_param,
    const float* __restrict__ scale,
    float* __restrict__ feat_ws,
    float* __restrict__ R_ws)
{
    __shared__ float c_sh[NT_ * M1 * BETA];
    __shared__ float s_sh[K_ * 25];
    __shared__ float sr_sh[K_ * 5];
    __shared__ float Rpart[2 * 96];
    __shared__ float R_sh[96];

    const int tid = threadIdx.x;
    const int bn = blockIdx.x;
    const int n  = bn % N_;
    const int tn = type_map[n];

    for (int i = tid; i < NT_ * M1 * BETA; i += 256)
        c_sh[i] = c_param[tn * (NT_ * M1 * BETA) + i];

    const int k  = tid;
    const int tk = k >> 7;
    const int lni = list_neigh[(size_t)bn * K_ + k];
    const float valid = (lni >= 0) ? 1.0f : 0.0f;

    const float4 dr4 = reinterpret_cast<const float4*>(imagedr)[(size_t)bn * K_ + k];
    const float rx = dr4.y, ry = dr4.z, rz = dr4.w;
    const float r  = sqrtf(rx*rx + ry*ry + rz*rz + 1e-12f);
    const float uraw = (r - RMINF) / LSPAN;
    const float u  = fminf(fmaxf(uraw, 0.0f), 1.0f);
    const float fc = 0.5f * (cosf(PI_F * u) + 1.0f) * valid;
    const float x  = 2.0f * (r - RMINF) / LSPAN - 1.0f;

    float T[BETA];
    T[0] = 1.0f; T[1] = x;
#pragma unroll
    for (int j = 2; j < BETA; ++j) T[j] = 2.0f * x * T[j-1] - T[j-2];

    const float inv_r = 1.0f / r;
    sr_sh[k * 5 + 0] = valid;
    sr_sh[k * 5 + 1] = valid * rx * inv_r;
    sr_sh[k * 5 + 2] = valid * ry * inv_r;
    sr_sh[k * 5 + 3] = valid * rz * inv_r;

    __syncthreads();   // c_sh ready

    const float* crow = &c_sh[tk * M1 * BETA];
#pragma unroll
    for (int f = 0; f < M1; ++f) {
        float a0 = 0.0f, a1 = 0.0f;
#pragma unroll
        for (int j = 0; j < BETA; j += 2) {
            a0 = fmaf(T[j],   crow[f * BETA + j],   a0);
            a1 = fmaf(T[j+1], crow[f * BETA + j+1], a1);
        }
        s_sh[k * 25 + f] = fc * (a0 + a1);
    }
    __syncthreads();

    if (tid < 192) {
        const int half = tid / 96, tt = tid % 96;
        const int f = tt >> 2, c = tt & 3;
        const int k0 = half * 128;
        float a0 = 0.0f, a1 = 0.0f;
        for (int kk = k0; kk < k0 + 128; kk += 2) {
            a0 = fmaf(s_sh[kk * 25 + f],     sr_sh[kk * 5 + c],     a0);
            a1 = fmaf(s_sh[(kk+1) * 25 + f], sr_sh[(kk+1) * 5 + c], a1);
        }
        Rpart[half * 96 + tt] = a0 + a1;
    }
    __syncthreads();
    if (tid < 96) {
        const float v = (Rpart[tid] + Rpart[96 + tid]) * (1.0f / MN_);
        R_sh[tid] = v;
        R_ws[(size_t)bn * 96 + tid] = v;
    }
    __syncthreads();
    if (tid < NFEAT) {
        const int f = tid / 6, g = tid % 6;
        float acc = 0.0f;
#pragma unroll
        for (int c = 0; c < 4; ++c) acc += R_sh[f * 4 + c] * R_sh[g * 4 + c];
        feat_ws[(size_t)bn * NFEAT + tid] = acc * scale[tid];
    }
}

// ---------------- K2: MLP fwd + bwd (2 atoms per block) ----------------
__global__ __launch_bounds__(256) void k2_mlp(
    const int*   __restrict__ type_map,
    const float* __restrict__ scale,
    const float* __restrict__ W0,
    const float* __restrict__ b0,
    const float* __restrict__ W1,
    const float* __restrict__ b1,
    const float* __restrict__ W2,
    const float* __restrict__ b2,
    const float* __restrict__ eshift,
    const float* __restrict__ feat_ws,
    float* __restrict__ dfeat_ws,     // may alias feat_ws
    float* __restrict__ out)
{
    __shared__ float feat_sh[2][NFEAT];
    __shared__ float h_sh[2][HID];
    __shared__ float dz1_sh[2][HID];
    __shared__ float dz0_sh[2][HID];
    __shared__ float red[4];

    const int tid = threadIdx.x;
    const int a   = tid >> 7;          // atom slot 0/1
    const int c   = tid & 127;         // column / row index
    const int lane = tid & 63;
    const int wid  = tid >> 6;
    const int bn = blockIdx.x * 2 + a;
    const int n  = bn % N_;
    const int tn = type_map[n];

    for (int i = tid; i < 2 * NFEAT; i += 256) {
        const int aa = i / NFEAT, f = i % NFEAT;
        feat_sh[aa][f] = feat_ws[(size_t)(blockIdx.x * 2 + aa) * NFEAT + f];
    }
    __syncthreads();

    // layer 0
    float acc0 = b0[tn * HID + c], acc0b = 0.0f;
    const float* w0c = W0 + (size_t)tn * NFEAT * HID + c;
#pragma unroll 8
    for (int f = 0; f < NFEAT; f += 2) {
        acc0  = fmaf(feat_sh[a][f],   w0c[f * HID],       acc0);
        acc0b = fmaf(feat_sh[a][f+1], w0c[(f+1) * HID],   acc0b);
    }
    const float h = tanhf(acc0 + acc0b);
    h_sh[a][c] = h;
    __syncthreads();

    // layer 1
    float acc1 = b1[tn * HID + c], acc1b = 0.0f;
    const float* w1c = W1 + (size_t)tn * HID * HID + c;
#pragma unroll 8
    for (int g = 0; g < HID; g += 2) {
        acc1  = fmaf(h_sh[a][g],   w1c[g * HID],       acc1);
        acc1b = fmaf(h_sh[a][g+1], w1c[(g+1) * HID],   acc1b);
    }
    const float t1 = tanhf(acc1 + acc1b);
    const float w2c = W2[tn * HID + c];
    const float dz1 = w2c * (1.0f - t1 * t1);
    dz1_sh[a][c] = dz1;

    // Ei = sum over c of (t1+h)*w2c
    {
        float v = (t1 + h) * w2c;
#pragma unroll
        for (int m = 32; m >= 1; m >>= 1) v += __shfl_xor(v, m);
        if (lane == 0) red[wid] = v;
    }
    __syncthreads();
    if (c == 0)
        out[EI_OFF + bn] = red[a * 2] + red[a * 2 + 1] + b2[tn] + eshift[tn];

    // dz0[h] = (W2[h] + sum_g W1[h][g]*dz1[g]) * (1-h^2)
    {
        const float4* w1row = reinterpret_cast<const float4*>(W1 + (size_t)(tn * HID + c) * HID);
        float ar = w2c, arb = 0.0f;
#pragma unroll 4
        for (int g4 = 0; g4 < HID / 4; g4 += 2) {
            const float4 w  = w1row[g4];
            const float4 w2 = w1row[g4 + 1];
            ar  += w.x  * dz1_sh[a][g4*4+0] + w.y  * dz1_sh[a][g4*4+1]
                 + w.z  * dz1_sh[a][g4*4+2] + w.w  * dz1_sh[a][g4*4+3];
            arb += w2.x * dz1_sh[a][g4*4+4] + w2.y * dz1_sh[a][g4*4+5]
                 + w2.z * dz1_sh[a][g4*4+6] + w2.w * dz1_sh[a][g4*4+7];
        }
        dz0_sh[a][c] = (ar + arb) * (1.0f - h * h);
    }
    __syncthreads();

    // dfeat[f] = scale[f] * sum_h W0[f][h] * dz0[h]
    for (int f = c; f < NFEAT; f += 128) {
        const float4* w0row = reinterpret_cast<const float4*>(W0 + (size_t)(tn * NFEAT + f) * HID);
        float ar = 0.0f, arb = 0.0f;
#pragma unroll 4
        for (int h4 = 0; h4 < HID / 4; h4 += 2) {
            const float4 w  = w0row[h4];
            const float4 w2 = w0row[h4 + 1];
            ar  += w.x  * dz0_sh[a][h4*4+0] + w.y  * dz0_sh[a][h4*4+1]
                 + w.z  * dz0_sh[a][h4*4+2] + w.w  * dz0_sh[a][h4*4+3];
            arb += w2.x * dz0_sh[a][h4*4+4] + w2.y * dz0_sh[a][h4*4+5]
                 + w2.z * dz0_sh[a][h4*4+6] + w2.w * dz0_sh[a][h4*4+7];
        }
        dfeat_ws[(size_t)bn * NFEAT + f] = (ar + arb) * scale[f];
    }
}

// ---------------- K3: embedding backward, G_ atoms/block, LDS force image ----------------
__global__ __launch_bounds__(256) void k3_bwd(
    const int*   __restrict__ list_neigh,
    const int*   __restrict__ type_map,
    const float* __restrict__ imagedr,
    const float* __restrict__ c_param,
    const float* __restrict__ dfeat_ws,
    const float* __restrict__ R_ws,
    float* __restrict__ contrib_ws,
    float* __restrict__ vir_ws)
{
    __shared__ float fcontrib[N_ * 3];      // 12 KB: force image for this batch
    __shared__ float c_sh[NT_ * M1 * BETA]; // 2.3 KB
    __shared__ float dfeat_sh[NFEAT];
    __shared__ float R_sh[96];
    __shared__ float dR_sh[96];
    __shared__ float red12[12 * 4];

    const int tid  = threadIdx.x;
    const int lane = tid & 63;
    const int wid  = tid >> 6;
    const int g  = blockIdx.x;            // 0..NG-1
    const int tk = tid >> 7;

    for (int i = tid; i < N_ * 3; i += 256) fcontrib[i] = 0.0f;

    float vv0=0.f,vv1=0.f,vv2=0.f,vv3=0.f,vv4=0.f,vv5=0.f,vv6=0.f,vv7=0.f,vv8=0.f;

    for (int aa = 0; aa < G_; ++aa) {
        const int bn = g * G_ + aa;
        const int n  = bn & (N_ - 1);
        const int tn = type_map[n];

        __syncthreads();   // previous iteration's users of shared bufs done
        for (int i = tid; i < NT_ * M1 * BETA; i += 256)
            c_sh[i] = c_param[tn * (NT_ * M1 * BETA) + i];
        if (tid < NFEAT) dfeat_sh[tid] = dfeat_ws[(size_t)bn * NFEAT + tid];
        if (tid < 96)    R_sh[tid]     = R_ws[(size_t)bn * 96 + tid];
        __syncthreads();

        if (tid < 96) {
            const int p = tid >> 2, c = tid & 3;
            float acc = 0.0f;
#pragma unroll
            for (int gg = 0; gg < M2; ++gg) acc += dfeat_sh[p * 6 + gg] * R_sh[gg * 4 + c];
            if (p < M2) {
                for (int f = 0; f < M1; ++f) acc += dfeat_sh[f * 6 + p] * R_sh[f * 4 + c];
            }
            dR_sh[p * 4 + c] = acc * (1.0f / MN_);
        }
        __syncthreads();

        const int lni = list_neigh[(size_t)bn * K_ + tid];
        const float valid = (lni >= 0) ? 1.0f : 0.0f;
        const float4 dr4 = reinterpret_cast<const float4*>(imagedr)[(size_t)bn * K_ + tid];
        const float rx = dr4.y, ry = dr4.z, rz = dr4.w;
        const float r  = sqrtf(rx*rx + ry*ry + rz*rz + 1e-12f);
        const float uraw = (r - RMINF) / LSPAN;
        const float u  = fminf(fmaxf(uraw, 0.0f), 1.0f);
        const float fc = 0.5f * (cosf(PI_F * u) + 1.0f) * valid;
        const float x  = 2.0f * (r - RMINF) / LSPAN - 1.0f;

        float T[BETA];
        T[0] = 1.0f; T[1] = x;
#pragma unroll
        for (int j = 2; j < BETA; ++j) T[j] = 2.0f * x * T[j-1] - T[j-2];

        const float inv_r = 1.0f / r;
        const float sr0 = valid;
        const float sr1 = valid * rx * inv_r;
        const float sr2 = valid * ry * inv_r;
        const float sr3 = valid * rz * inv_r;

        const float* crow = &c_sh[tk * M1 * BETA];
        float cj[BETA];
#pragma unroll
        for (int j = 0; j < BETA; ++j) cj[j] = 0.0f;
        float dsr1 = 0.0f, dsr2 = 0.0f, dsr3 = 0.0f, dfc = 0.0f;
#pragma unroll
        for (int f = 0; f < M1; ++f) {
            float sa = 0.0f, sb = 0.0f;
#pragma unroll
            for (int j = 0; j < BETA; j += 2) {
                sa = fmaf(T[j],   crow[f * BETA + j],   sa);
                sb = fmaf(T[j+1], crow[f * BETA + j+1], sb);
            }
            const float sf = sa + sb;
            const float d0 = dR_sh[f*4+0], d1 = dR_sh[f*4+1], d2 = dR_sh[f*4+2], d3 = dR_sh[f*4+3];
            const float dsf = d0 * sr0 + d1 * sr1 + d2 * sr2 + d3 * sr3;
            dfc += dsf * sf;
            const float dsg = dsf * fc;
#pragma unroll
            for (int j = 0; j < BETA; ++j) cj[j] = fmaf(dsg, crow[f * BETA + j], cj[j]);
            const float sk = fc * sf;
            dsr1 = fmaf(d1, sk, dsr1); dsr2 = fmaf(d2, sk, dsr2); dsr3 = fmaf(d3, sk, dsr3);
        }
        float dx = cj[1];
        float tpm1 = 1.0f, tpm2 = 0.0f;
#pragma unroll
        for (int j = 2; j < BETA; ++j) {
            const float tp = 2.0f * T[j-1] + 2.0f * x * tpm1 - tpm2;
            dx = fmaf(cj[j], tp, dx);
            tpm2 = tpm1; tpm1 = tp;
        }
        float dfcdr = 0.0f;
        if (uraw > 0.0f && uraw < 1.0f)
            dfcdr = -0.5f * PI_F * sinf(PI_F * u) * valid / LSPAN;
        const float drt = dx * (2.0f / LSPAN) + dfc * dfcdr;
        const float Sdot = dsr1 * rx + dsr2 * ry + dsr3 * rz;
        const float common = drt * inv_r - valid * Sdot * inv_r * inv_r * inv_r;
        const float gx = common * rx + valid * dsr1 * inv_r;
        const float gy = common * ry + valid * dsr2 * inv_r;
        const float gz = common * rz + valid * dsr3 * inv_r;

        // neighbor scatter into LDS force image
        if (lni >= 0) {
            atomicAdd(&fcontrib[lni * 3 + 0], -gx);
            atomicAdd(&fcontrib[lni * 3 + 1], -gy);
            atomicAdd(&fcontrib[lni * 3 + 2], -gz);
        }

        // self-force: block reduce then one LDS add
        {
            float s0 = gx, s1 = gy, s2 = gz;
#pragma unroll
            for (int m = 32; m >= 1; m >>= 1) {
                s0 += __shfl_xor(s0, m);
                s1 += __shfl_xor(s1, m);
                s2 += __shfl_xor(s2, m);
            }
            if (lane == 0) {
                red12[0 * 4 + wid] = s0;
                red12[1 * 4 + wid] = s1;
                red12[2 * 4 + wid] = s2;
            }
        }
        __syncthreads();
        if (tid < 3) {
            const float v = red12[tid*4+0] + red12[tid*4+1] + red12[tid*4+2] + red12[tid*4+3];
            atomicAdd(&fcontrib[n * 3 + tid], v);
        }

        // virial accumulate (per-thread, across atoms)
        vv0 = fmaf(-rx, gx, vv0); vv1 = fmaf(-rx, gy, vv1); vv2 = fmaf(-rx, gz, vv2);
        vv3 = fmaf(-ry, gx, vv3); vv4 = fmaf(-ry, gy, vv4); vv5 = fmaf(-ry, gz, vv5);
        vv6 = fmaf(-rz, gx, vv6); vv7 = fmaf(-rz, gy, vv7); vv8 = fmaf(-rz, gz, vv8);
    }

    // virial block reduce -> vir_ws[g][9]
    {
        float vals[9] = {vv0,vv1,vv2,vv3,vv4,vv5,vv6,vv7,vv8};
        __syncthreads();   // red12 free
#pragma unroll
        for (int i = 0; i < 9; ++i) {
            float v = vals[i];
#pragma unroll
            for (int m = 32; m >= 1; m >>= 1) v += __shfl_xor(v, m);
            if (lane == 0) red12[i * 4 + wid] = v;
        }
        __syncthreads();
        if (tid < 9)
            vir_ws[(size_t)g * 9 + tid] = red12[tid*4+0] + red12[tid*4+1]
                                        + red12[tid*4+2] + red12[tid*4+3];
    }

    // flush LDS force image -> contrib (coalesced, non-atomic)
    __syncthreads();
    {
        float4* dst = reinterpret_cast<float4*>(contrib_ws + (size_t)g * (N_ * 3));
        const float4* src = reinterpret_cast<const float4*>(fcontrib);
        for (int i = tid; i < (N_ * 3) / 4; i += 256) dst[i] = src[i];
    }
}

// ---------------- K3R: sliced column-sum of contrib ----------------
__global__ __launch_bounds__(256) void k3_reduce(
    const float* __restrict__ contrib_ws,
    float* __restrict__ partial_ws)
{
    const int x  = blockIdx.x;          // SL*B_*3 blocks
    const int ch = x % 3;
    const int bb = (x / 3) % B_;
    const int s  = x / (3 * B_);
    const int c4 = ch * 256 + threadIdx.x;        // float4 column, 0..767
    const int rows = (NG / B_) / SL;              // 256/8 = 32 rows per slice
    const int g0 = bb * (NG / B_) + s * rows;

    const float4* src = reinterpret_cast<const float4*>(contrib_ws);
    float4 a0 = {0,0,0,0}, a1 = {0,0,0,0};
    for (int r = 0; r < rows; r += 2) {
        const float4 v0 = src[(size_t)(g0 + r)     * 768 + c4];
        const float4 v1 = src[(size_t)(g0 + r + 1) * 768 + c4];
        a0.x += v0.x; a0.y += v0.y; a0.z += v0.z; a0.w += v0.w;
        a1.x += v1.x; a1.y += v1.y; a1.z += v1.z; a1.w += v1.w;
    }
    const float4 res = {a0.x + a1.x, a0.y + a1.y, a0.z + a1.z, a0.w + a1.w};
    reinterpret_cast<float4*>(partial_ws)[(size_t)(s * B_ + bb) * 768 + c4] = res;
}

// ---------------- K4: finalize Force, Etot, Virial ----------------
__global__ __launch_bounds__(256) void k4_final(
    const float* __restrict__ vir_ws,
    const float* __restrict__ partial_ws,
    float* __restrict__ out)
{
    __shared__ float red[10 * 4];
    const int tid  = threadIdx.x;
    const int lane = tid & 63;
    const int wid  = tid >> 6;
    const int b = blockIdx.x;

    // Force: merge SL slice partials, write directly (no zero pass needed)
    for (int i = tid; i < N_ * 3; i += 256) {
        float f = 0.0f;
#pragma unroll
        for (int s = 0; s < SL; ++s) f += partial_ws[(size_t)(s * B_ + b) * (N_ * 3) + i];
        out[F_OFF + (size_t)b * (N_ * 3) + i] = f;
    }

    float vals[10];
#pragma unroll
    for (int i = 0; i < 10; ++i) vals[i] = 0.0f;
    for (int n = tid; n < N_; n += 256) vals[0] += out[EI_OFF + b * N_ + n];
    {   // one vir row per thread (256 rows per batch)
        const float* vp = vir_ws + ((size_t)b * (NG / B_) + tid) * 9;
#pragma unroll
        for (int j = 0; j < 9; ++j) vals[1 + j] = vp[j];
    }
#pragma unroll
    for (int i = 0; i < 10; ++i) {
        float v = vals[i];
#pragma unroll
        for (int m = 32; m >= 1; m >>= 1) v += __shfl_xor(v, m);
        if (lane == 0) red[i * 4 + wid] = v;
    }
    __syncthreads();
    if (tid < 10) {
        const float v = red[tid*4+0] + red[tid*4+1] + red[tid*4+2] + red[tid*4+3];
        if (tid == 0) out[b] = v;
        else          out[V_OFF + b * 9 + (tid - 1)] = v;
    }
}

extern "C" void kernel_launch(void* const* d_in, const int* in_sizes, int n_in,
                              void* d_out, int out_size, void* d_ws, size_t ws_size,
                              hipStream_t stream) {
    float* out = (float*)d_out;
    float* ws  = (float*)d_ws;
    float* feat_ws    = ws + WS_FEAT;
    float* R_ws       = ws + WS_R;
    float* vir_ws     = ws + WS_VIR;
    float* contrib_ws = ws + WS_CONTRIB;
    float* partial_ws = ws + WS_PARTIAL;

    const int*   list_neigh = (const int*)d_in[0];
    const int*   type_map   = (const int*)d_in[1];
    const float* imagedr    = (const float*)d_in[3];
    const float* c_param    = (const float*)d_in[6];
    const float* scale      = (const float*)d_in[7];
    const float* W0 = (const float*)d_in[8];
    const float* b0 = (const float*)d_in[9];
    const float* W1 = (const float*)d_in[10];
    const float* b1 = (const float*)d_in[11];
    const float* W2 = (const float*)d_in[12];
    const float* b2 = (const float*)d_in[13];
    const float* eshift = (const float*)d_in[14];

    k1_embed<<<B_ * N_, 256, 0, stream>>>(list_neigh, type_map, imagedr, c_param,
                                          scale, feat_ws, R_ws);
    k2_mlp<<<B_ * N_ / 2, 256, 0, stream>>>(type_map, scale, W0, b0, W1, b1, W2, b2,
                                            eshift, feat_ws, feat_ws /*alias dfeat*/, out);
    k3_bwd<<<NG, 256, 0, stream>>>(list_neigh, type_map, imagedr, c_param,
                                   feat_ws /*dfeat*/, R_ws, contrib_ws, vir_ws);
    k3_reduce<<<SL * B_ * 3, 256, 0, stream>>>(contrib_ws, partial_ws);
    k4_final<<<B_, 256, 0, stream>>>(vir_ws, partial_ws, out);
}

// Round 9
// 194.414 us; speedup vs baseline: 4.2709x; 1.6605x over previous
//
#include <hip/hip_runtime.h>
#include <math.h>

#define RMINF  0.5f
#define LSPAN  5.5f          // RC - RMIN
constexpr int BETA = 12, M1 = 24, M2 = 6;
constexpr int B_ = 4, N_ = 1024, NT_ = 2, MN_ = 128;
constexpr int K_ = NT_ * MN_;        // 256
constexpr int NFEAT = M1 * M2;       // 144
constexpr int HID = 128;
constexpr float PI_F = 3.14159265358979323846f;

// Output layout: Etot(4) | Ei(4096) | Force(4*1024*3) | Virial(36)
constexpr int EI_OFF = B_;                  // 4
constexpr int F_OFF  = B_ + B_ * N_;        // 4100
constexpr int V_OFF  = F_OFF + B_ * N_ * 3; // 16388

constexpr int G_ = 4;                 // source atoms per k3 block
constexpr int NG = B_ * N_ / G_;      // 1024 k3 blocks
constexpr int SL = 8;                 // reduce slices

// Workspace layout (floats); total ~16.9 MB
constexpr size_t WS_FEAT    = 0;                          // 4096*144
constexpr size_t WS_R       = (size_t)B_ * N_ * NFEAT;    // 4096*96
constexpr size_t WS_VIR     = WS_R + (size_t)B_ * N_ * 96;      // 1024*9
constexpr size_t WS_CONTRIB = WS_VIR + (size_t)NG * 9;          // 1024*3072
constexpr size_t WS_PARTIAL = WS_CONTRIB + (size_t)NG * N_ * 3; // 8*4*3072

// NOTE: no occupancy-floor arg on launch_bounds anywhere. (256,4) capped the
// allocator at 64 VGPR -> per-thread arrays spilled to scratch -> ~2 GB HBM
// traffic (rounds 4/6). Round 8 confirmed: VGPR 220, WRITE 12 MB, 104 us.

// ---------------- K1: embedding forward -> feat, R ----------------
// Algebraic form: M[tk][j][c] = sum_k fc*T_j*sr_c ; R = (c_param . M)/MN.
__global__ __launch_bounds__(256) void k1_embed(
    const int*   __restrict__ list_neigh,
    const int*   __restrict__ type_map,
    const float* __restrict__ imagedr,
    const float* __restrict__ c_param,
    const float* __restrict__ scale,
    float* __restrict__ feat_ws,
    float* __restrict__ R_ws)
{
    __shared__ float c_sh[NT_ * M1 * BETA];   // [tk][f][j] 576
    __shared__ float p_sh[K_][13];            // fc*T_j, padded
    __shared__ float sr_sh[K_][5];
    __shared__ float Mpart[2][96];            // [sub][tk*48 + j*4 + c]
    __shared__ float R_sh[96];

    const int tid = threadIdx.x;
    const int bn = blockIdx.x;
    const int n  = bn % N_;
    const int tn = type_map[n];

    for (int i = tid; i < NT_ * M1 * BETA; i += 256)
        c_sh[i] = c_param[tn * (NT_ * M1 * BETA) + i];

    const int k = tid;
    const int lni = list_neigh[(size_t)bn * K_ + k];
    const float valid = (lni >= 0) ? 1.0f : 0.0f;

    const float4 dr4 = reinterpret_cast<const float4*>(imagedr)[(size_t)bn * K_ + k];
    const float rx = dr4.y, ry = dr4.z, rz = dr4.w;
    const float r  = sqrtf(rx*rx + ry*ry + rz*rz + 1e-12f);
    const float uraw = (r - RMINF) / LSPAN;
    const float u  = fminf(fmaxf(uraw, 0.0f), 1.0f);
    const float fc = 0.5f * (cosf(PI_F * u) + 1.0f) * valid;
    const float x  = 2.0f * (r - RMINF) / LSPAN - 1.0f;

    float T[BETA];
    T[0] = 1.0f; T[1] = x;
#pragma unroll
    for (int j = 2; j < BETA; ++j) T[j] = 2.0f * x * T[j-1] - T[j-2];

    const float inv_r = 1.0f / r;
    sr_sh[k][0] = valid;
    sr_sh[k][1] = valid * rx * inv_r;
    sr_sh[k][2] = valid * ry * inv_r;
    sr_sh[k][3] = valid * rz * inv_r;
#pragma unroll
    for (int j = 0; j < BETA; ++j) p_sh[k][j] = fc * T[j];
    __syncthreads();

    // M partial: 192 threads, each sums 64 neighbors for one (tk,j,c)
    if (tid < 192) {
        const int sub = tid / 96, idx = tid % 96;
        const int tk = idx / 48, rem = idx % 48;
        const int j = rem >> 2, cc = rem & 3;
        const int k0 = tk * 128 + sub * 64;
        float a0 = 0.0f, a1 = 0.0f;
        for (int kk = k0; kk < k0 + 64; kk += 2) {
            a0 = fmaf(p_sh[kk][j],   sr_sh[kk][cc],   a0);
            a1 = fmaf(p_sh[kk+1][j], sr_sh[kk+1][cc], a1);
        }
        Mpart[sub][idx] = a0 + a1;
    }
    __syncthreads();

    // R[f][c] = (1/MN) sum_tk sum_j c[tk][f][j] * M[tk][j][c]
    if (tid < 96) {
        const int f = tid >> 2, cc = tid & 3;
        float acc = 0.0f;
#pragma unroll
        for (int tk = 0; tk < NT_; ++tk) {
#pragma unroll
            for (int j = 0; j < BETA; ++j) {
                const float m = Mpart[0][tk*48 + j*4 + cc] + Mpart[1][tk*48 + j*4 + cc];
                acc = fmaf(c_sh[tk*288 + f*12 + j], m, acc);
            }
        }
        const float v = acc * (1.0f / MN_);
        R_sh[tid] = v;
        R_ws[(size_t)bn * 96 + tid] = v;
    }
    __syncthreads();
    if (tid < NFEAT) {
        const int f = tid / 6, g = tid % 6;
        float acc = 0.0f;
#pragma unroll
        for (int c = 0; c < 4; ++c) acc += R_sh[f * 4 + c] * R_sh[g * 4 + c];
        feat_ws[(size_t)bn * NFEAT + tid] = acc * scale[tid];
    }
}

// ---------------- K2: MLP fwd + bwd, 8 atoms (2 n x 4 b) per block --------
__global__ __launch_bounds__(256) void k2_mlp(
    const int*   __restrict__ type_map,
    const float* __restrict__ scale,
    const float* __restrict__ W0,
    const float* __restrict__ b0,
    const float* __restrict__ W1,
    const float* __restrict__ b1,
    const float* __restrict__ W2,
    const float* __restrict__ b2,
    const float* __restrict__ eshift,
    const float* __restrict__ feat_ws,
    float* __restrict__ dfeat_ws,     // may alias feat_ws
    float* __restrict__ out)
{
    __shared__ float feat_sh[2][4][NFEAT];
    __shared__ float h_sh[2][4][HID];
    __shared__ float dz1_sh[2][4][HID];
    __shared__ float dz0_sh[2][4][HID];
    __shared__ float red[4][4];       // [wave][b]

    const int tid  = threadIdx.x;
    const int half = tid >> 7;        // which n
    const int c    = tid & 127;
    const int lane = tid & 63;
    const int wid  = tid >> 6;
    const int n0 = blockIdx.x * 2;
    const int n_h = n0 + half;
    const int tn = type_map[n_h];     // same type for all 4 b of this n

    for (int i = tid; i < 8 * NFEAT; i += 256) {
        const int a = i / NFEAT, f = i % NFEAT;
        const int hh = a >> 2, bb = a & 3;
        feat_sh[hh][bb][f] = feat_ws[((size_t)bb * N_ + n0 + hh) * NFEAT + f];
    }
    __syncthreads();

    // layer 0: 4 atoms per thread, one weight stream
    float acc[4];
    const float bias0 = b0[tn * HID + c];
#pragma unroll
    for (int b = 0; b < 4; ++b) acc[b] = bias0;
    const float* w0c = W0 + (size_t)tn * NFEAT * HID + c;
#pragma unroll 4
    for (int f = 0; f < NFEAT; ++f) {
        const float w = w0c[(size_t)f * HID];
#pragma unroll
        for (int b = 0; b < 4; ++b) acc[b] = fmaf(feat_sh[half][b][f], w, acc[b]);
    }
    float hv[4];
#pragma unroll
    for (int b = 0; b < 4; ++b) { hv[b] = tanhf(acc[b]); h_sh[half][b][c] = hv[b]; }
    __syncthreads();

    // layer 1
    const float bias1 = b1[tn * HID + c];
#pragma unroll
    for (int b = 0; b < 4; ++b) acc[b] = bias1;
    const float* w1c = W1 + (size_t)tn * HID * HID + c;
#pragma unroll 4
    for (int g = 0; g < HID; ++g) {
        const float w = w1c[(size_t)g * HID];
#pragma unroll
        for (int b = 0; b < 4; ++b) acc[b] = fmaf(h_sh[half][b][g], w, acc[b]);
    }
    const float w2c = W2[tn * HID + c];
    float ei[4];
#pragma unroll
    for (int b = 0; b < 4; ++b) {
        const float t1 = tanhf(acc[b]);
        dz1_sh[half][b][c] = w2c * (1.0f - t1 * t1);
        ei[b] = (t1 + hv[b]) * w2c;
    }
#pragma unroll
    for (int b = 0; b < 4; ++b) {
        float v = ei[b];
#pragma unroll
        for (int m = 32; m >= 1; m >>= 1) v += __shfl_xor(v, m);
        if (lane == 0) red[wid][b] = v;
    }
    __syncthreads();   // red + dz1_sh ready
    if (tid < 8) {
        const int hh = tid >> 2, bb = tid & 3;
        const int nn = n0 + hh;
        const int tt = type_map[nn];
        out[EI_OFF + (size_t)bb * N_ + nn] =
            red[hh*2][bb] + red[hh*2+1][bb] + b2[tt] + eshift[tt];
    }

    // dz0[b][c] = (W2[c] + sum_g W1[c][g] dz1[b][g]) * (1-h^2)
    {
        const float4* w1row = reinterpret_cast<const float4*>(W1 + (size_t)(tn * HID + c) * HID);
        float ar[4];
#pragma unroll
        for (int b = 0; b < 4; ++b) ar[b] = w2c;
#pragma unroll 2
        for (int g4 = 0; g4 < HID / 4; ++g4) {
            const float4 w = w1row[g4];
#pragma unroll
            for (int b = 0; b < 4; ++b) {
                ar[b] += w.x * dz1_sh[half][b][g4*4+0] + w.y * dz1_sh[half][b][g4*4+1]
                       + w.z * dz1_sh[half][b][g4*4+2] + w.w * dz1_sh[half][b][g4*4+3];
            }
        }
#pragma unroll
        for (int b = 0; b < 4; ++b) dz0_sh[half][b][c] = ar[b] * (1.0f - hv[b] * hv[b]);
    }
    __syncthreads();

    // dfeat rows f = c (+128 for c<16)
    for (int f = c; f < NFEAT; f += HID) {
        const float4* w0row = reinterpret_cast<const float4*>(W0 + (size_t)(tn * NFEAT + f) * HID);
        float ar[4] = {0.0f, 0.0f, 0.0f, 0.0f};
#pragma unroll 2
        for (int h4 = 0; h4 < HID / 4; ++h4) {
            const float4 w = w0row[h4];
#pragma unroll
            for (int b = 0; b < 4; ++b) {
                ar[b] += w.x * dz0_sh[half][b][h4*4+0] + w.y * dz0_sh[half][b][h4*4+1]
                       + w.z * dz0_sh[half][b][h4*4+2] + w.w * dz0_sh[half][b][h4*4+3];
            }
        }
        const float sc = scale[f];
#pragma unroll
        for (int b = 0; b < 4; ++b)
            dfeat_ws[((size_t)b * N_ + n_h) * NFEAT + f] = ar[b] * sc;
    }
}

// ---------------- K3: embedding backward via A = c . dR ------------------
__global__ __launch_bounds__(256) void k3_bwd(
    const int*   __restrict__ list_neigh,
    const int*   __restrict__ type_map,
    const float* __restrict__ imagedr,
    const float* __restrict__ c_param,
    const float* __restrict__ dfeat_ws,
    const float* __restrict__ R_ws,
    float* __restrict__ contrib_ws,
    float* __restrict__ vir_ws)
{
    __shared__ float fcontrib[N_ * 3];      // 12 KB force image
    __shared__ float c_sh[NT_ * M1 * BETA];
    __shared__ float dfeat_sh[NFEAT];
    __shared__ float R_sh[96];
    __shared__ float dR_sh[96];
    __shared__ float A_sh[96];              // [tk][j][c]
    __shared__ float red12[12 * 4];

    const int tid  = threadIdx.x;
    const int lane = tid & 63;
    const int wid  = tid >> 6;
    const int g  = blockIdx.x;
    const int tk = tid >> 7;

    for (int i = tid; i < N_ * 3; i += 256) fcontrib[i] = 0.0f;

    float vv0=0.f,vv1=0.f,vv2=0.f,vv3=0.f,vv4=0.f,vv5=0.f,vv6=0.f,vv7=0.f,vv8=0.f;

    for (int aa = 0; aa < G_; ++aa) {
        const int bn = g * G_ + aa;
        const int n  = bn & (N_ - 1);
        const int tn = type_map[n];

        __syncthreads();
        for (int i = tid; i < NT_ * M1 * BETA; i += 256)
            c_sh[i] = c_param[tn * (NT_ * M1 * BETA) + i];
        if (tid < NFEAT) dfeat_sh[tid] = dfeat_ws[(size_t)bn * NFEAT + tid];
        if (tid < 96)    R_sh[tid]     = R_ws[(size_t)bn * 96 + tid];
        __syncthreads();

        if (tid < 96) {
            const int p = tid >> 2, c = tid & 3;
            float acc = 0.0f;
#pragma unroll
            for (int gg = 0; gg < M2; ++gg) acc += dfeat_sh[p * 6 + gg] * R_sh[gg * 4 + c];
            if (p < M2) {
                for (int f = 0; f < M1; ++f) acc += dfeat_sh[f * 6 + p] * R_sh[f * 4 + c];
            }
            dR_sh[p * 4 + c] = acc * (1.0f / MN_);
        }
        __syncthreads();

        // A[tk][j][c] = sum_f c[tk][f][j] * dR[f][c]
        if (tid < 96) {
            const int atk = tid / 48, rem = tid % 48;
            const int j = rem >> 2, cc = rem & 3;
            float acc = 0.0f;
#pragma unroll
            for (int f = 0; f < M1; ++f)
                acc = fmaf(c_sh[atk*288 + f*12 + j], dR_sh[f*4 + cc], acc);
            A_sh[tid] = acc;
        }
        __syncthreads();

        const int lni = list_neigh[(size_t)bn * K_ + tid];
        const float valid = (lni >= 0) ? 1.0f : 0.0f;
        const float4 dr4 = reinterpret_cast<const float4*>(imagedr)[(size_t)bn * K_ + tid];
        const float rx = dr4.y, ry = dr4.z, rz = dr4.w;
        const float r  = sqrtf(rx*rx + ry*ry + rz*rz + 1e-12f);
        const float uraw = (r - RMINF) / LSPAN;
        const float u  = fminf(fmaxf(uraw, 0.0f), 1.0f);
        const float fc = 0.5f * (cosf(PI_F * u) + 1.0f) * valid;
        const float x  = 2.0f * (r - RMINF) / LSPAN - 1.0f;

        float T[BETA];
        T[0] = 1.0f; T[1] = x;
#pragma unroll
        for (int j = 2; j < BETA; ++j) T[j] = 2.0f * x * T[j-1] - T[j-2];

        const float inv_r = 1.0f / r;
        const float sr0 = valid;
        const float sr1 = valid * rx * inv_r;
        const float sr2 = valid * ry * inv_r;
        const float sr3 = valid * rz * inv_r;

        // single 12-iter contraction: cj_j = A[j].sr ; dfc = T.cj ;
        // tA_c = T.A[:,c] ; dx = cj.T'
        const float* Arow = &A_sh[tk * 48];
        float dfc = 0.0f, dx = 0.0f;
        float tA0 = 0.0f, tA1 = 0.0f, tA2 = 0.0f, tA3 = 0.0f;
        float tpm1 = 1.0f, tpm2 = 0.0f;
#pragma unroll
        for (int j = 0; j < BETA; ++j) {
            const float a0 = Arow[j*4+0], a1 = Arow[j*4+1];
            const float a2 = Arow[j*4+2], a3 = Arow[j*4+3];
            const float cjj = a0*sr0 + a1*sr1 + a2*sr2 + a3*sr3;
            dfc = fmaf(T[j], cjj, dfc);
            tA0 = fmaf(T[j], a0, tA0);
            tA1 = fmaf(T[j], a1, tA1);
            tA2 = fmaf(T[j], a2, tA2);
            tA3 = fmaf(T[j], a3, tA3);
            if (j == 1) {
                dx = cjj;                  // T'_1 = 1
            } else if (j >= 2) {
                const float tp = 2.0f * T[j-1] + 2.0f * x * tpm1 - tpm2;
                dx = fmaf(cjj, tp, dx);
                tpm2 = tpm1; tpm1 = tp;
            }
        }
        const float dsr1 = fc * tA1, dsr2 = fc * tA2, dsr3 = fc * tA3;

        float dfcdr = 0.0f;
        if (uraw > 0.0f && uraw < 1.0f)
            dfcdr = -0.5f * PI_F * sinf(PI_F * u) * valid / LSPAN;
        const float drt = (fc * dx) * (2.0f / LSPAN) + dfc * dfcdr;
        const float Sdot = dsr1 * rx + dsr2 * ry + dsr3 * rz;
        const float common = drt * inv_r - valid * Sdot * inv_r * inv_r * inv_r;
        const float gx = common * rx + valid * dsr1 * inv_r;
        const float gy = common * ry + valid * dsr2 * inv_r;
        const float gz = common * rz + valid * dsr3 * inv_r;

        if (lni >= 0) {
            atomicAdd(&fcontrib[lni * 3 + 0], -gx);
            atomicAdd(&fcontrib[lni * 3 + 1], -gy);
            atomicAdd(&fcontrib[lni * 3 + 2], -gz);
        }

        {
            float s0 = gx, s1 = gy, s2 = gz;
#pragma unroll
            for (int m = 32; m >= 1; m >>= 1) {
                s0 += __shfl_xor(s0, m);
                s1 += __shfl_xor(s1, m);
                s2 += __shfl_xor(s2, m);
            }
            if (lane == 0) {
                red12[0 * 4 + wid] = s0;
                red12[1 * 4 + wid] = s1;
                red12[2 * 4 + wid] = s2;
            }
        }
        __syncthreads();
        if (tid < 3) {
            const float v = red12[tid*4+0] + red12[tid*4+1] + red12[tid*4+2] + red12[tid*4+3];
            atomicAdd(&fcontrib[n * 3 + tid], v);
        }

        vv0 = fmaf(-rx, gx, vv0); vv1 = fmaf(-rx, gy, vv1); vv2 = fmaf(-rx, gz, vv2);
        vv3 = fmaf(-ry, gx, vv3); vv4 = fmaf(-ry, gy, vv4); vv5 = fmaf(-ry, gz, vv5);
        vv6 = fmaf(-rz, gx, vv6); vv7 = fmaf(-rz, gy, vv7); vv8 = fmaf(-rz, gz, vv8);
    }

    {
        float vals[9] = {vv0,vv1,vv2,vv3,vv4,vv5,vv6,vv7,vv8};
        __syncthreads();
#pragma unroll
        for (int i = 0; i < 9; ++i) {
            float v = vals[i];
#pragma unroll
            for (int m = 32; m >= 1; m >>= 1) v += __shfl_xor(v, m);
            if (lane == 0) red12[i * 4 + wid] = v;
        }
        __syncthreads();
        if (tid < 9)
            vir_ws[(size_t)g * 9 + tid] = red12[tid*4+0] + red12[tid*4+1]
                                        + red12[tid*4+2] + red12[tid*4+3];
    }

    __syncthreads();
    {
        float4* dst = reinterpret_cast<float4*>(contrib_ws + (size_t)g * (N_ * 3));
        const float4* src = reinterpret_cast<const float4*>(fcontrib);
        for (int i = tid; i < (N_ * 3) / 4; i += 256) dst[i] = src[i];
    }
}

// ---------------- K3R: sliced column-sum of contrib ----------------
__global__ __launch_bounds__(256) void k3_reduce(
    const float* __restrict__ contrib_ws,
    float* __restrict__ partial_ws)
{
    const int x  = blockIdx.x;          // SL*B_*3 blocks
    const int ch = x % 3;
    const int bb = (x / 3) % B_;
    const int s  = x / (3 * B_);
    const int c4 = ch * 256 + threadIdx.x;
    const int rows = (NG / B_) / SL;
    const int g0 = bb * (NG / B_) + s * rows;

    const float4* src = reinterpret_cast<const float4*>(contrib_ws);
    float4 a0 = {0,0,0,0}, a1 = {0,0,0,0};
    for (int r = 0; r < rows; r += 2) {
        const float4 v0 = src[(size_t)(g0 + r)     * 768 + c4];
        const float4 v1 = src[(size_t)(g0 + r + 1) * 768 + c4];
        a0.x += v0.x; a0.y += v0.y; a0.z += v0.z; a0.w += v0.w;
        a1.x += v1.x; a1.y += v1.y; a1.z += v1.z; a1.w += v1.w;
    }
    const float4 res = {a0.x + a1.x, a0.y + a1.y, a0.z + a1.z, a0.w + a1.w};
    reinterpret_cast<float4*>(partial_ws)[(size_t)(s * B_ + bb) * 768 + c4] = res;
}

// ---------------- K4: finalize Force, Etot, Virial ----------------
__global__ __launch_bounds__(256) void k4_final(
    const float* __restrict__ vir_ws,
    const float* __restrict__ partial_ws,
    float* __restrict__ out)
{
    __shared__ float red[10 * 4];
    const int tid  = threadIdx.x;
    const int lane = tid & 63;
    const int wid  = tid >> 6;
    const int b = blockIdx.x;

    for (int i = tid; i < N_ * 3; i += 256) {
        float f = 0.0f;
#pragma unroll
        for (int s = 0; s < SL; ++s) f += partial_ws[(size_t)(s * B_ + b) * (N_ * 3) + i];
        out[F_OFF + (size_t)b * (N_ * 3) + i] = f;
    }

    float vals[10];
#pragma unroll
    for (int i = 0; i < 10; ++i) vals[i] = 0.0f;
    for (int n = tid; n < N_; n += 256) vals[0] += out[EI_OFF + b * N_ + n];
    {
        const float* vp = vir_ws + ((size_t)b * (NG / B_) + tid) * 9;
#pragma unroll
        for (int j = 0; j < 9; ++j) vals[1 + j] = vp[j];
    }
#pragma unroll
    for (int i = 0; i < 10; ++i) {
        float v = vals[i];
#pragma unroll
        for (int m = 32; m >= 1; m >>= 1) v += __shfl_xor(v, m);
        if (lane == 0) red[i * 4 + wid] = v;
    }
    __syncthreads();
    if (tid < 10) {
        const float v = red[tid*4+0] + red[tid*4+1] + red[tid*4+2] + red[tid*4+3];
        if (tid == 0) out[b] = v;
        else          out[V_OFF + b * 9 + (tid - 1)] = v;
    }
}

extern "C" void kernel_launch(void* const* d_in, const int* in_sizes, int n_in,
                              void* d_out, int out_size, void* d_ws, size_t ws_size,
                              hipStream_t stream) {
    float* out = (float*)d_out;
    float* ws  = (float*)d_ws;
    float* feat_ws    = ws + WS_FEAT;
    float* R_ws       = ws + WS_R;
    float* vir_ws     = ws + WS_VIR;
    float* contrib_ws = ws + WS_CONTRIB;
    float* partial_ws = ws + WS_PARTIAL;

    const int*   list_neigh = (const int*)d_in[0];
    const int*   type_map   = (const int*)d_in[1];
    const float* imagedr    = (const float*)d_in[3];
    const float* c_param    = (const float*)d_in[6];
    const float* scale      = (const float*)d_in[7];
    const float* W0 = (const float*)d_in[8];
    const float* b0 = (const float*)d_in[9];
    const float* W1 = (const float*)d_in[10];
    const float* b1 = (const float*)d_in[11];
    const float* W2 = (const float*)d_in[12];
    const float* b2 = (const float*)d_in[13];
    const float* eshift = (const float*)d_in[14];

    k1_embed<<<B_ * N_, 256, 0, stream>>>(list_neigh, type_map, imagedr, c_param,
                                          scale, feat_ws, R_ws);
    k2_mlp<<<N_ / 2, 256, 0, stream>>>(type_map, scale, W0, b0, W1, b1, W2, b2,
                                       eshift, feat_ws, feat_ws /*alias dfeat*/, out);
    k3_bwd<<<NG, 256, 0, stream>>>(list_neigh, type_map, imagedr, c_param,
                                   feat_ws /*dfeat*/, R_ws, contrib_ws, vir_ws);
    k3_reduce<<<SL * B_ * 3, 256, 0, stream>>>(contrib_ws, partial_ws);
    k4_final<<<B_, 256, 0, stream>>>(vir_ws, partial_ws, out);
}